// Round 12
// baseline (365.340 us; speedup 1.0000x reference)
//
#include <hip/hip_runtime.h>
#include <hip/hip_bf16.h>
#include <math.h>

#define B_   4
#define C_   192
#define N_   6400
#define K_   9
#define M_   50
#define TK_  12
#define OC_  192
#define KC_  576     // 3*C
#define CH_  200     // 32-point chunks per batch
#define PC_  32      // points per chunk
#define LSTR 53      // padded lg row stride (fp32; odd -> conflict-free)
#define TSTR 40      // lgT/xT row stride (bf16), 80 B, 16B-aligned
#define GSTR 40      // k_gemm bf16 LDS row stride

typedef __bf16 b16x8 __attribute__((ext_vector_type(8)));
typedef float f32x4 __attribute__((ext_vector_type(4)));

__device__ inline unsigned short f2b(float f) {
    union { __hip_bfloat16 h; unsigned short u; } v;
    v.h = __float2bfloat16(f);
    return v.u;
}
__device__ inline float b2f(unsigned short u) {
    union { float f; unsigned int i; } v;
    v.i = ((unsigned int)u) << 16;
    return v.f;
}

// ---------------- W re-permute -> bf16: Wg16[o][t*192+ch] = conv_w[o][ch*3+t]
__global__ void k_rearrange_w(const float* __restrict__ cw, unsigned short* __restrict__ Wg16) {
    int g = blockIdx.x * 256 + threadIdx.x;           // < 192*576
    int o = g / KC_, r = g % KC_;
    int t = r / C_, ch = r % C_;
    Wg16[g] = f2b(cw[o * KC_ + ch * 3 + t]);
}

// -------- transpose x (b,c,n) -> xt fp32 + xt16 (bf16 hi) + xt16l (bf16 lo) --
__global__ void k_transpose(const float* __restrict__ x, float* __restrict__ xt,
                            unsigned short* __restrict__ xt16,
                            unsigned short* __restrict__ xt16l) {
    __shared__ float tile[32][33];
    int b = blockIdx.z;
    int p0 = blockIdx.x * 32, c0 = blockIdx.y * 32;
    int tx = threadIdx.x, ty = threadIdx.y;
    const float* xb = x + (size_t)b * C_ * N_;
    float* xtb = xt + (size_t)b * N_ * C_;
    unsigned short* xt16b = xt16 + (size_t)b * N_ * C_;
    unsigned short* xt16lb = xt16l + (size_t)b * N_ * C_;
#pragma unroll
    for (int i = 0; i < 4; i++) {
        int cc = ty + 8 * i;
        tile[cc][tx] = xb[(size_t)(c0 + cc) * N_ + p0 + tx];
    }
    __syncthreads();
#pragma unroll
    for (int i = 0; i < 4; i++) {
        int pp = ty + 8 * i;
        float v = tile[tx][pp];
        size_t o = (size_t)(p0 + pp) * C_ + c0 + tx;
        xtb[o] = v;
        unsigned short hi = f2b(v);
        xt16b[o] = hi;
        xt16lb[o] = f2b(v - b2f(hi));
    }
}

// -- initial centroids: 5x10 pool (+ |c|^2, + hi/lo split, zero pad rows) -----
__global__ __launch_bounds__(192) void k_init_cent(const float* __restrict__ xt,
        float* __restrict__ cent, float* __restrict__ c2,
        unsigned short* __restrict__ centh, unsigned short* __restrict__ centl) {
    int m = blockIdx.x, b = blockIdx.y, c = threadIdx.x;
    if (m >= M_) {   // zero-pad rows 50..63 of the split arrays
        size_t o = ((size_t)b * 64 + m) * C_ + c;
        centh[o] = 0; centl[o] = 0;
        return;
    }
    int gy = m / 10, gx = m % 10;
    const float* xtb = xt + (size_t)b * N_ * C_;
    float s = 0.f;
    for (int yy = 0; yy < 16; yy++)
        for (int xx = 0; xx < 8; xx++) {
            int p = (gy * 16 + yy) * 80 + gx * 8 + xx;
            s += xtb[(size_t)p * C_ + c];
        }
    float v = s * (1.f / 128.f);
    cent[((size_t)b * M_ + m) * C_ + c] = v;
    size_t oh = ((size_t)b * 64 + m) * C_ + c;
    unsigned short hi = f2b(v);
    centh[oh] = hi;
    centl[oh] = f2b(v - b2f(hi));
    float q = v * v;
    __shared__ float red[3];
#pragma unroll
    for (int off = 32; off > 0; off >>= 1) q += __shfl_down(q, off, 64);
    if ((c & 63) == 0) red[c >> 6] = q;
    __syncthreads();
    if (c == 0) c2[(size_t)b * M_ + m] = red[0] + red[1] + red[2];
}

// ==== fused (32-point blocks, 800 total): logits (MFMA fast / fp32 exact) +
//      softmax + bf16-split MFMA partials (+ topk on last iter) ==============
// LDS layout (43520 B):
//  Ac fp32 [16][68] @ 0..4352 ; Bp fp32 [16][36] @ 4352..6656   (exact only)
//  lg fp32 [32][LSTR] @ 6656..13440
//  xTh [208][40] @ 0..16640 ; xTl @ 16640..33280   (built after lg dead)
//  lgTh [64][40] @ 33280..38400 ; lgTl @ 38400..43520
__global__ __launch_bounds__(256) void k_logits_upd(const float* __restrict__ xt,
        const unsigned short* __restrict__ xt16, const unsigned short* __restrict__ xt16l,
        const float* __restrict__ cent,
        const unsigned short* __restrict__ centh, const unsigned short* __restrict__ centl,
        const float* __restrict__ c2g,
        float* __restrict__ part, float* __restrict__ wsp,
        int* __restrict__ nn, int do_topk, int fast) {
    __shared__ alignas(16) char smem[43520];
    __shared__ float sred[256];
    float* Ac = (float*)smem;
    float* Bp = (float*)(smem + 4352);
    float* lg = (float*)(smem + 6656);
    unsigned short* xTh = (unsigned short*)smem;
    unsigned short* xTl = (unsigned short*)(smem + 16640);
    unsigned short* lgTh = (unsigned short*)(smem + 33280);
    unsigned short* lgTl = (unsigned short*)(smem + 38400);
    int b = blockIdx.y;
    int blk = blockIdx.x;
    int p0 = blk * PC_;
    int tid = threadIdx.x;
    int tx = tid & 15, ty = tid >> 4;
    int lr = tid >> 2, lq = tid & 3;
    int wave = tid >> 6, lane = tid & 63;
    int m16 = lane & 15, q = lane >> 4;
    const float* xb = xt + ((size_t)b * N_ + p0) * C_;
    const unsigned short* x16b = xt16 + ((size_t)b * N_ + p0) * C_;
    const unsigned short* x16lb = xt16l + ((size_t)b * N_ + p0) * C_;
    if (fast) {
        // ---- phase 1 fast: split-bf16 MFMA logits, fragments direct from
        //      global. wave -> (p-tile = wave&1, m-tiles {wave>>1, wave>>1+2})
        const unsigned short* chg = centh + (size_t)b * 64 * C_;
        const unsigned short* clg = centl + (size_t)b * 64 * C_;
        int pt = wave & 1, mt0 = wave >> 1;
        f32x4 acc1[2];
        acc1[0] = (f32x4){0.f, 0.f, 0.f, 0.f};
        acc1[1] = (f32x4){0.f, 0.f, 0.f, 0.f};
#pragma unroll
        for (int kt = 0; kt < 6; kt++) {
            int kg = kt * 32;
            size_t xo = (size_t)(pt * 16 + m16) * C_ + kg + q * 8;
            b16x8 bh = *(const b16x8*)&x16b[xo];
            b16x8 bl = *(const b16x8*)&x16lb[xo];
#pragma unroll
            for (int i = 0; i < 2; i++) {
                int mt = mt0 + 2 * i;
                size_t co = (size_t)(mt * 16 + m16) * C_ + kg + q * 8;
                b16x8 ah = *(const b16x8*)&chg[co];
                b16x8 al = *(const b16x8*)&clg[co];
                acc1[i] = __builtin_amdgcn_mfma_f32_16x16x32_bf16(ah, bh, acc1[i], 0, 0, 0);
                acc1[i] = __builtin_amdgcn_mfma_f32_16x16x32_bf16(ah, bl, acc1[i], 0, 0, 0);
                acc1[i] = __builtin_amdgcn_mfma_f32_16x16x32_bf16(al, bh, acc1[i], 0, 0, 0);
            }
        }
        // D row m = mt*16+q*4+r, col p = pt*16+m16
#pragma unroll
        for (int i = 0; i < 2; i++) {
            int mt = mt0 + 2 * i;
#pragma unroll
            for (int r = 0; r < 4; r++) {
                int m = mt * 16 + q * 4 + r;
                if (m < M_) {
                    float c2v = c2g[(size_t)b * M_ + m];
                    lg[(pt * 16 + m16) * LSTR + m] = 2.f * acc1[i][r] - c2v;
                }
            }
        }
    } else {
        // ---- phase 1 exact: fp32 VALU logits (iter 2 -> topk), 32p x 64m ----
        const float* cb = cent + (size_t)b * M_ * C_;
        float acc[4][2];
#pragma unroll
        for (int i = 0; i < 4; i++) { acc[i][0] = 0.f; acc[i][1] = 0.f; }
        for (int kt = 0; kt < 12; kt++) {
            int kg = kt * 16;
            float4 cv = make_float4(0.f, 0.f, 0.f, 0.f);
            if (lr < M_) cv = *(const float4*)&cb[(size_t)lr * C_ + kg + 4 * lq];
            float4 pv = make_float4(0.f, 0.f, 0.f, 0.f);
            if (tid < 128) pv = *(const float4*)&xb[(size_t)(tid >> 2) * C_ + kg + 4 * lq];
            __syncthreads();
            Ac[(4 * lq + 0) * 68 + lr] = cv.x; Ac[(4 * lq + 1) * 68 + lr] = cv.y;
            Ac[(4 * lq + 2) * 68 + lr] = cv.z; Ac[(4 * lq + 3) * 68 + lr] = cv.w;
            if (tid < 128) {
                int xr = tid >> 2;
                Bp[(4 * lq + 0) * 36 + xr] = pv.x; Bp[(4 * lq + 1) * 36 + xr] = pv.y;
                Bp[(4 * lq + 2) * 36 + xr] = pv.z; Bp[(4 * lq + 3) * 36 + xr] = pv.w;
            }
            __syncthreads();
#pragma unroll
            for (int kk = 0; kk < 16; kk++) {
                float4 a = *(const float4*)&Ac[kk * 68 + 4 * ty];
                float2 bb = *(const float2*)&Bp[kk * 36 + 2 * tx];
                acc[0][0] += a.x * bb.x; acc[0][1] += a.x * bb.y;
                acc[1][0] += a.y * bb.x; acc[1][1] += a.y * bb.y;
                acc[2][0] += a.z * bb.x; acc[2][1] += a.z * bb.y;
                acc[3][0] += a.w * bb.x; acc[3][1] += a.w * bb.y;
            }
        }
        __syncthreads();
#pragma unroll
        for (int i = 0; i < 4; i++) {
            int m = 4 * ty + i;
            if (m < M_) {
                float c2v = c2g[(size_t)b * M_ + m];
                lg[(2 * tx + 0) * LSTR + m] = 2.f * acc[i][0] - c2v;
                lg[(2 * tx + 1) * LSTR + m] = 2.f * acc[i][1] - c2v;
            }
        }
    }
    __syncthreads();
    // ---- softmax (8-way parallel per row, 32 rows) ----
    {
        int p = tid & 31, prt = tid >> 5;
        int m0 = prt * 6;
        int m1 = (prt == 7) ? M_ : m0 + 6;
        float* row = &lg[p * LSTR];
        float mx = -1e30f;
        for (int m = m0; m < m1; m++) mx = fmaxf(mx, row[m]);
        sred[prt * 32 + p] = mx;
        __syncthreads();
        mx = sred[p];
#pragma unroll
        for (int k = 1; k < 8; k++) mx = fmaxf(mx, sred[k * 32 + p]);
        float s = 0.f;
        for (int m = m0; m < m1; m++) {
            float e = expf(row[m] - mx);
            row[m] = e;
            s += e;
        }
        __syncthreads();
        sred[prt * 32 + p] = s;
        __syncthreads();
        s = sred[p];
#pragma unroll
        for (int k = 1; k < 8; k++) s += sred[k * 32 + p];
        float inv = 1.f / s;
        for (int m = m0; m < m1; m++) row[m] *= inv;
    }
    __syncthreads();
    // ---- build lgT[m][p] hi/lo bf16 (lane-consecutive p: conflict-free) ----
    for (int j = tid; j < 64 * PC_; j += 256) {
        int m = j >> 5, p = j & 31;
        float w = (m < M_) ? lg[p * LSTR + m] : 0.f;
        unsigned short hi = f2b(w);
        lgTh[m * TSTR + p] = hi;
        lgTl[m * TSTR + p] = f2b(w - b2f(hi));
    }
    __syncthreads();
    // ---- topk on last iteration (reads+destroys lg; before xT overwrites) ---
    if (do_topk && tid < PC_) {
        float* row = &lg[tid * LSTR];
        int* nb = nn + ((size_t)b * N_ + p0 + tid) * TK_;
        for (int r = 0; r < TK_; r++) {
            float bv = -1.f;
            int bi = 0;
            for (int m = 0; m < M_; m++) {
                float v = row[m];
                if (v > bv) { bv = v; bi = m; }   // strict > : lowest index wins ties
            }
            nb[r] = bi;
            row[bi] = -1.f;
        }
    }
    __syncthreads();   // lg fully dead; xT may overwrite
    // ---- xT build: [c][p] hi/lo bf16, lane-consecutive p (conflict-free) ----
    for (int j = tid; j < PC_ * 24; j += 256) {
        int pl = j & 31, ko = (j >> 5) * 8;
        int4 vh = *(const int4*)&x16b[(size_t)pl * C_ + ko];
        int4 vl = *(const int4*)&x16lb[(size_t)pl * C_ + ko];
        const unsigned short* ph = (const unsigned short*)&vh;
        const unsigned short* pv = (const unsigned short*)&vl;
#pragma unroll
        for (int i = 0; i < 8; i++) {
            xTh[(ko + i) * TSTR + pl] = ph[i];
            xTl[(ko + i) * TSTR + pl] = pv[i];
        }
    }
    for (int j = tid; j < PC_ * 16; j += 256) {
        int pl = j & 31, c = C_ + (j >> 5);
        xTh[c * TSTR + pl] = (c == C_) ? f2b(1.f) : 0;
        xTl[c * TSTR + pl] = 0;
    }
    __syncthreads();
    // ---- phase 2: part[m][c] = sum_p w*x via 3-term bf16-split MFMA (k=32) --
    f32x4 acc2[13];
#pragma unroll
    for (int i = 0; i < 13; i++) acc2[i] = (f32x4){0.f, 0.f, 0.f, 0.f};
    {
        b16x8 ah = *(const b16x8*)&lgTh[(wave * 16 + m16) * TSTR + q * 8];
        b16x8 al = *(const b16x8*)&lgTl[(wave * 16 + m16) * TSTR + q * 8];
#pragma unroll
        for (int ct = 0; ct < 13; ct++) {
            b16x8 bh = *(const b16x8*)&xTh[(ct * 16 + m16) * TSTR + q * 8];
            b16x8 bl = *(const b16x8*)&xTl[(ct * 16 + m16) * TSTR + q * 8];
            acc2[ct] = __builtin_amdgcn_mfma_f32_16x16x32_bf16(ah, bh, acc2[ct], 0, 0, 0);
            acc2[ct] = __builtin_amdgcn_mfma_f32_16x16x32_bf16(ah, bl, acc2[ct], 0, 0, 0);
            acc2[ct] = __builtin_amdgcn_mfma_f32_16x16x32_bf16(al, bh, acc2[ct], 0, 0, 0);
        }
    }
    // ---- epilogue: D row m = wave*16 + q*4 + r, col c = ct*16 + m16 ----
    float* pb = part + ((size_t)b * CH_ + blk) * (size_t)(M_ * C_);
    int mbase = wave * 16 + q * 4;
#pragma unroll
    for (int ct = 0; ct < 13; ct++) {
        int c = ct * 16 + m16;
#pragma unroll
        for (int r = 0; r < 4; r++) {
            int mm = mbase + r;
            if (mm >= M_) continue;
            float v = acc2[ct][r];
            if (c < C_) pb[(size_t)mm * C_ + c] = v;
            else if (c == C_) wsp[((size_t)b * CH_ + blk) * M_ + mm] = v;
        }
    }
}

__global__ __launch_bounds__(192) void k_upd_reduce(const float* __restrict__ part,
        const float* __restrict__ wsp, float* __restrict__ cent, float* __restrict__ c2,
        unsigned short* __restrict__ cent16,
        unsigned short* __restrict__ centh, unsigned short* __restrict__ centl, int last) {
    int m = blockIdx.x, b = blockIdx.y, c = threadIdx.x;
    __shared__ float sws;
    __shared__ float red[3];
    if (c == 0) {
        float s = 0.f;
        for (int ch = 0; ch < CH_; ch++) s += wsp[((size_t)b * CH_ + ch) * M_ + m];
        sws = s + 1e-8f;
    }
    float s = 0.f;
    for (int ch = 0; ch < CH_; ch++)
        s += part[(((size_t)b * CH_ + ch) * M_ + m) * (size_t)C_ + c];
    __syncthreads();
    float v = s / sws;
    size_t o = ((size_t)b * M_ + m) * C_ + c;
    cent[o] = v;
    if (last) cent16[o] = f2b(v);
    size_t oh = ((size_t)b * 64 + m) * C_ + c;
    unsigned short hi = f2b(v);
    centh[oh] = hi;
    centl[oh] = f2b(v - b2f(hi));
    float q = v * v;
#pragma unroll
    for (int off = 32; off > 0; off >>= 1) q += __shfl_down(q, off, 64);
    if ((c & 63) == 0) red[c >> 6] = q;
    __syncthreads();
    if (c == 0) c2[(size_t)b * M_ + m] = red[0] + red[1] + red[2];
}

// ---------------- gathers (bf16 sources): edge max-rel + topk-centroid max ---
__global__ __launch_bounds__(192) void k_gather(const unsigned short* __restrict__ xt16,
        const unsigned short* __restrict__ cent16, const int* __restrict__ edge,
        const int* __restrict__ nn, unsigned short* __restrict__ xjt16,
        unsigned short* __restrict__ xjct16) {
    __shared__ int sidx[2 * K_ + TK_];
    int p = blockIdx.x, b = blockIdx.y, c = threadIdx.x;
    if (c < K_)
        sidx[c] = edge[((size_t)b * N_ + p) * K_ + c];
    else if (c < 2 * K_)
        sidx[c] = edge[(size_t)B_ * N_ * K_ + ((size_t)b * N_ + p) * K_ + (c - K_)];
    else if (c < 2 * K_ + TK_)
        sidx[c] = nn[((size_t)b * N_ + p) * TK_ + (c - 2 * K_)];
    __syncthreads();
    const unsigned short* xb = xt16 + (size_t)b * N_ * C_;
    const unsigned short* cbv = cent16 + (size_t)b * M_ * C_;
    float xv = b2f(xb[(size_t)p * C_ + c]);
    float mj = -1e30f;
#pragma unroll
    for (int kk = 0; kk < K_; kk++) {
        float vj = b2f(xb[(size_t)sidx[kk] * C_ + c]);
        float vi = b2f(xb[(size_t)sidx[K_ + kk] * C_ + c]);
        mj = fmaxf(mj, vj - vi);
    }
    float mc = -1e30f;
#pragma unroll
    for (int kk = 0; kk < TK_; kk++)
        mc = fmaxf(mc, b2f(cbv[(size_t)sidx[2 * K_ + kk] * C_ + c]));
    size_t o = ((size_t)b * N_ + p) * C_ + c;
    xjt16[o] = f2b(mj);
    xjct16[o] = f2b(mc - xv);
}

// ------- final conv via bf16 MFMA: full-OC 192(o) x 64(p) tile, feat read once
__global__ __launch_bounds__(256) void k_gemm(const unsigned short* __restrict__ Wg16,
        const unsigned short* __restrict__ xt16, const unsigned short* __restrict__ xjt16,
        const unsigned short* __restrict__ xjct16, const float* __restrict__ bias,
        float* __restrict__ out) {
    __shared__ short As[192 * GSTR];   // Wg k-chunk [o][32k]
    __shared__ short Bs[64 * GSTR];    // feat k-chunk [p][32k]
    int b = blockIdx.y;
    int po = blockIdx.x * 64;
    int tid = threadIdx.x;
    int wave = tid >> 6, lane = tid & 63;
    int m16 = lane & 15, q = lane >> 4;
    const unsigned short* s0 = xt16 + (size_t)b * N_ * C_;
    const unsigned short* s1 = xjt16 + (size_t)b * N_ * C_;
    const unsigned short* s2 = xjct16 + (size_t)b * N_ * C_;
    f32x4 acc[12];
#pragma unroll
    for (int i = 0; i < 12; i++) acc[i] = (f32x4){0.f, 0.f, 0.f, 0.f};
    int brow = tid >> 2, bch = tid & 3;
    for (int kt = 0; kt < 18; kt++) {
        int kg = kt * 32;
        int prt = kg / C_, koff = kg - prt * C_;
        const unsigned short* src = (prt == 0) ? s0 : ((prt == 1) ? s1 : s2);
        int4 av[3];
#pragma unroll
        for (int t = 0; t < 3; t++) {
            int idx = t * 256 + tid;
            av[t] = *(const int4*)&Wg16[(size_t)(idx >> 2) * KC_ + kg + (idx & 3) * 8];
        }
        int4 bv = *(const int4*)&src[(size_t)(po + brow) * C_ + koff + bch * 8];
        __syncthreads();
#pragma unroll
        for (int t = 0; t < 3; t++) {
            int idx = t * 256 + tid;
            *(int4*)&As[(idx >> 2) * GSTR + (idx & 3) * 8] = av[t];
        }
        *(int4*)&Bs[brow * GSTR + bch * 8] = bv;
        __syncthreads();
        b16x8 bf = *(const b16x8*)&Bs[(wave * 16 + m16) * GSTR + q * 8];
#pragma unroll
        for (int of = 0; of < 12; of++) {
            b16x8 af = *(const b16x8*)&As[(of * 16 + m16) * GSTR + q * 8];
            acc[of] = __builtin_amdgcn_mfma_f32_16x16x32_bf16(af, bf, acc[of], 0, 0, 0);
        }
    }
    int p = po + wave * 16 + m16;
#pragma unroll
    for (int of = 0; of < 12; of++) {
        int o = of * 16 + q * 4;
        float4 bv = *(const float4*)&bias[o];
        float bia[4] = {bv.x, bv.y, bv.z, bv.w};
#pragma unroll
        for (int r = 0; r < 4; r++)
            out[((size_t)b * OC_ + o + r) * N_ + p] = fmaxf(acc[of][r] + bia[r], 0.f);
    }
}

extern "C" void kernel_launch(void* const* d_in, const int* in_sizes, int n_in,
                              void* d_out, int out_size, void* d_ws, size_t ws_size,
                              hipStream_t stream) {
    (void)in_sizes; (void)n_in; (void)out_size; (void)ws_size;
    const float* x   = (const float*)d_in[0];
    const int* edge  = (const int*)d_in[1];
    const float* cw  = (const float*)d_in[2];
    const float* cbi = (const float*)d_in[3];
    float* ws = (float*)d_ws;
    size_t o = 0;
    float* xt   = ws + o; o += (size_t)B_ * N_ * C_;
    unsigned short* xt16 = (unsigned short*)(ws + o); o += (size_t)B_ * N_ * C_ / 2;
    unsigned short* xt16l = (unsigned short*)(ws + o); o += (size_t)B_ * N_ * C_ / 2;
    unsigned short* Wg16 = (unsigned short*)(ws + o); o += (size_t)OC_ * KC_ / 2;
    float* cent = ws + o; o += (size_t)B_ * M_ * C_;
    unsigned short* cent16 = (unsigned short*)(ws + o); o += (size_t)B_ * M_ * C_ / 2;
    unsigned short* centh = (unsigned short*)(ws + o); o += (size_t)B_ * 64 * C_ / 2;
    unsigned short* centl = (unsigned short*)(ws + o); o += (size_t)B_ * 64 * C_ / 2;
    float* c2   = ws + o; o += (size_t)B_ * M_;
    float* part = ws + o; o += (size_t)B_ * CH_ * M_ * C_;
    float* wsp  = ws + o; o += (size_t)B_ * CH_ * M_;
    int* nn = (int*)(ws + o); o += (size_t)B_ * N_ * TK_;
    unsigned short* xjt16  = (unsigned short*)(ws + o); o += (size_t)B_ * N_ * C_ / 2;
    unsigned short* xjct16 = (unsigned short*)(ws + o); o += (size_t)B_ * N_ * C_ / 2;
    float* outp = (float*)d_out;

    k_rearrange_w<<<dim3(432), dim3(256), 0, stream>>>(cw, Wg16);
    k_transpose<<<dim3(N_ / 32, C_ / 32, B_), dim3(32, 8), 0, stream>>>(x, xt, xt16, xt16l);
    k_init_cent<<<dim3(64, B_), dim3(192), 0, stream>>>(xt, cent, c2, centh, centl);
    for (int it = 0; it < 3; it++) {
        k_logits_upd<<<dim3(CH_, B_), dim3(256), 0, stream>>>(xt, xt16, xt16l, cent,
            centh, centl, c2, part, wsp, nn, (it == 2) ? 1 : 0, (it < 2) ? 1 : 0);
        k_upd_reduce<<<dim3(M_, B_), dim3(192), 0, stream>>>(part, wsp, cent, c2,
            cent16, centh, centl, (it == 2) ? 1 : 0);
    }
    k_gather<<<dim3(N_, B_), dim3(192), 0, stream>>>(xt16, cent16, edge, nn, xjt16, xjct16);
    k_gemm<<<dim3(N_ / 64, B_), dim3(256), 0, stream>>>(Wg16, xt16, xjt16, xjct16, cbi, outp);
}

// Round 13
// 290.229 us; speedup vs baseline: 1.2588x; 1.2588x over previous
//
#include <hip/hip_runtime.h>
#include <hip/hip_bf16.h>
#include <math.h>

#define B_   4
#define C_   192
#define N_   6400
#define K_   9
#define M_   50
#define TK_  12
#define OC_  192
#define KC_  576     // 3*C
#define CH_  100     // 64-point chunks per batch
#define LSTR 53      // padded lg row stride (fp32; odd -> conflict-free)
#define TSTR 72      // lgT row stride (bf16)
#define XSTR 40      // xT row stride (bf16), 80 B, 16B-aligned
#define GSTR 40      // k_gemm bf16 LDS row stride

typedef __bf16 b16x8 __attribute__((ext_vector_type(8)));
typedef float f32x4 __attribute__((ext_vector_type(4)));

__device__ inline unsigned short f2b(float f) {
    union { __hip_bfloat16 h; unsigned short u; } v;
    v.h = __float2bfloat16(f);
    return v.u;
}
__device__ inline float b2f(unsigned short u) {
    union { float f; unsigned int i; } v;
    v.i = ((unsigned int)u) << 16;
    return v.f;
}

// -------- transpose x (b,c,n) -> xt fp32 + xt16/xt16l (bf16 hi/lo)
//          + merged W re-permute (blocks with blockIdx.x >= 200) -------------
__global__ void k_transpose(const float* __restrict__ x, float* __restrict__ xt,
                            unsigned short* __restrict__ xt16,
                            unsigned short* __restrict__ xt16l,
                            const float* __restrict__ cw,
                            unsigned short* __restrict__ Wg16) {
    int tid = threadIdx.y * 32 + threadIdx.x;
    if (blockIdx.x >= 200) {
        // Wg16[o][t*192+ch] = conv_w[o][ch*3+t];  432 blocks x 256 = 110592
        int g = ((blockIdx.x - 200) * 24 + blockIdx.z * 6 + blockIdx.y) * 256 + tid;
        if (g < OC_ * KC_) {
            int r = g % KC_;
            Wg16[g] = f2b(cw[(g / KC_) * KC_ + (r % C_) * 3 + (r / C_)]);
        }
        return;
    }
    __shared__ float tile[32][33];
    int b = blockIdx.z;
    int p0 = blockIdx.x * 32, c0 = blockIdx.y * 32;
    int tx = threadIdx.x, ty = threadIdx.y;
    const float* xb = x + (size_t)b * C_ * N_;
    float* xtb = xt + (size_t)b * N_ * C_;
    unsigned short* xt16b = xt16 + (size_t)b * N_ * C_;
    unsigned short* xt16lb = xt16l + (size_t)b * N_ * C_;
#pragma unroll
    for (int i = 0; i < 4; i++) {
        int cc = ty + 8 * i;
        tile[cc][tx] = xb[(size_t)(c0 + cc) * N_ + p0 + tx];
    }
    __syncthreads();
#pragma unroll
    for (int i = 0; i < 4; i++) {
        int pp = ty + 8 * i;
        float v = tile[tx][pp];
        size_t o = (size_t)(p0 + pp) * C_ + c0 + tx;
        xtb[o] = v;
        unsigned short hi = f2b(v);
        xt16b[o] = hi;
        xt16lb[o] = f2b(v - b2f(hi));
    }
}

// -- initial centroids: 5x10 pool (+ |c|^2, + hi/lo split, zero pad rows) -----
__global__ __launch_bounds__(192) void k_init_cent(const float* __restrict__ xt,
        float* __restrict__ cent, float* __restrict__ c2,
        unsigned short* __restrict__ centh, unsigned short* __restrict__ centl) {
    int m = blockIdx.x, b = blockIdx.y, c = threadIdx.x;
    if (m >= M_) {   // zero-pad rows 50..63 of the split arrays
        size_t o = ((size_t)b * 64 + m) * C_ + c;
        centh[o] = 0; centl[o] = 0;
        return;
    }
    int gy = m / 10, gx = m % 10;
    const float* xtb = xt + (size_t)b * N_ * C_;
    float s = 0.f;
    for (int yy = 0; yy < 16; yy++)
        for (int xx = 0; xx < 8; xx++) {
            int p = (gy * 16 + yy) * 80 + gx * 8 + xx;
            s += xtb[(size_t)p * C_ + c];
        }
    float v = s * (1.f / 128.f);
    cent[((size_t)b * M_ + m) * C_ + c] = v;
    size_t oh = ((size_t)b * 64 + m) * C_ + c;
    unsigned short hi = f2b(v);
    centh[oh] = hi;
    centl[oh] = f2b(v - b2f(hi));
    float q = v * v;
    __shared__ float red[3];
#pragma unroll
    for (int off = 32; off > 0; off >>= 1) q += __shfl_down(q, off, 64);
    if ((c & 63) == 0) red[c >> 6] = q;
    __syncthreads();
    if (c == 0) c2[(size_t)b * M_ + m] = red[0] + red[1] + red[2];
}

// ==== fused: logits (direct-global MFMA fast path / fp32 exact path) +
//      softmax + bf16-split MFMA partials (+ topk on last iter) ==============
__global__ __launch_bounds__(256) void k_logits_upd(const float* __restrict__ xt,
        const unsigned short* __restrict__ xt16, const unsigned short* __restrict__ xt16l,
        const float* __restrict__ cent,
        const unsigned short* __restrict__ centh, const unsigned short* __restrict__ centl,
        const float* __restrict__ c2g,
        unsigned short* __restrict__ part, float* __restrict__ wsp,
        int* __restrict__ nn, int do_topk, int fast) {
    __shared__ alignas(16) char smem[51712];
    __shared__ float sred[256];
    float* Ac = (float*)smem;                             // fp32 path staging
    float* Bp = (float*)(smem + 4352);
    float* lg = (float*)(smem + 20480);
    unsigned short* lgTh = (unsigned short*)smem;
    unsigned short* lgTl = (unsigned short*)(smem + 9216);
    unsigned short* xTh = (unsigned short*)(smem + 18432);
    unsigned short* xTl = (unsigned short*)(smem + 35072);
    int b = blockIdx.y;
    int blk = blockIdx.x;
    int p0 = blk * 64;
    int tid = threadIdx.x;
    int tx = tid & 15, ty = tid >> 4;
    int lr = tid >> 2, lq = tid & 3;
    int wave = tid >> 6, lane = tid & 63;
    int m16 = lane & 15, q = lane >> 4;
    const float* xb = xt + ((size_t)b * N_ + p0) * C_;
    const unsigned short* x16b = xt16 + ((size_t)b * N_ + p0) * C_;
    const unsigned short* x16lb = xt16l + ((size_t)b * N_ + p0) * C_;
    if (fast) {
        // ---- phase 1 fast: split-bf16 MFMA logits, fragments direct from
        //      global (xt16/centh already in [row][k] fragment layout) ----
        const unsigned short* chg = centh + (size_t)b * 64 * C_;
        const unsigned short* clg = centl + (size_t)b * 64 * C_;
        f32x4 acc1[4];
#pragma unroll
        for (int i = 0; i < 4; i++) acc1[i] = (f32x4){0.f, 0.f, 0.f, 0.f};
#pragma unroll
        for (int kt = 0; kt < 6; kt++) {
            int kg = kt * 32;
            size_t xo = (size_t)(wave * 16 + m16) * C_ + kg + q * 8;
            b16x8 bh = *(const b16x8*)&x16b[xo];
            b16x8 bl = *(const b16x8*)&x16lb[xo];
#pragma unroll
            for (int mt = 0; mt < 4; mt++) {
                size_t co = (size_t)(mt * 16 + m16) * C_ + kg + q * 8;
                b16x8 ah = *(const b16x8*)&chg[co];
                b16x8 al = *(const b16x8*)&clg[co];
                acc1[mt] = __builtin_amdgcn_mfma_f32_16x16x32_bf16(ah, bh, acc1[mt], 0, 0, 0);
                acc1[mt] = __builtin_amdgcn_mfma_f32_16x16x32_bf16(ah, bl, acc1[mt], 0, 0, 0);
                acc1[mt] = __builtin_amdgcn_mfma_f32_16x16x32_bf16(al, bh, acc1[mt], 0, 0, 0);
            }
        }
        // D row m = mt*16+q*4+r, col p = wave*16+m16
#pragma unroll
        for (int mt = 0; mt < 4; mt++) {
#pragma unroll
            for (int r = 0; r < 4; r++) {
                int m = mt * 16 + q * 4 + r;
                if (m < M_) {
                    float c2v = c2g[(size_t)b * M_ + m];
                    lg[(wave * 16 + m16) * LSTR + m] = 2.f * acc1[mt][r] - c2v;
                }
            }
        }
    } else {
        // ---- phase 1 exact: fp32 VALU logits (iter 2 -> topk) ----
        const float* cb = cent + (size_t)b * M_ * C_;
        float acc[4][4];
#pragma unroll
        for (int i = 0; i < 4; i++)
#pragma unroll
            for (int j = 0; j < 4; j++) acc[i][j] = 0.f;
        for (int kt = 0; kt < 12; kt++) {
            int kg = kt * 16;
            float4 cv = make_float4(0.f, 0.f, 0.f, 0.f);
            if (lr < M_) cv = *(const float4*)&cb[(size_t)lr * C_ + kg + 4 * lq];
            float4 pv = *(const float4*)&xb[(size_t)lr * C_ + kg + 4 * lq];
            __syncthreads();
            Ac[(4 * lq + 0) * 68 + lr] = cv.x; Ac[(4 * lq + 1) * 68 + lr] = cv.y;
            Ac[(4 * lq + 2) * 68 + lr] = cv.z; Ac[(4 * lq + 3) * 68 + lr] = cv.w;
            Bp[(4 * lq + 0) * 68 + lr] = pv.x; Bp[(4 * lq + 1) * 68 + lr] = pv.y;
            Bp[(4 * lq + 2) * 68 + lr] = pv.z; Bp[(4 * lq + 3) * 68 + lr] = pv.w;
            __syncthreads();
#pragma unroll
            for (int kk = 0; kk < 16; kk++) {
                float4 a = *(const float4*)&Ac[kk * 68 + 4 * ty];
                float4 bb = *(const float4*)&Bp[kk * 68 + 4 * tx];
                acc[0][0] += a.x * bb.x; acc[0][1] += a.x * bb.y; acc[0][2] += a.x * bb.z; acc[0][3] += a.x * bb.w;
                acc[1][0] += a.y * bb.x; acc[1][1] += a.y * bb.y; acc[1][2] += a.y * bb.z; acc[1][3] += a.y * bb.w;
                acc[2][0] += a.z * bb.x; acc[2][1] += a.z * bb.y; acc[2][2] += a.z * bb.z; acc[2][3] += a.z * bb.w;
                acc[3][0] += a.w * bb.x; acc[3][1] += a.w * bb.y; acc[3][2] += a.w * bb.z; acc[3][3] += a.w * bb.w;
            }
        }
        __syncthreads();
#pragma unroll
        for (int i = 0; i < 4; i++) {
            int m = 4 * ty + i;
            if (m < M_) {
                float c2v = c2g[(size_t)b * M_ + m];
#pragma unroll
                for (int j = 0; j < 4; j++)
                    lg[(4 * tx + j) * LSTR + m] = 2.f * acc[i][j] - c2v;
            }
        }
    }
    __syncthreads();
    // ---- softmax (4-way parallel per row) ----
    {
        int p = tid & 63, prt = tid >> 6;
        int m0 = prt * 13;
        int m1 = (prt == 3) ? M_ : m0 + 13;
        float* row = &lg[p * LSTR];
        float mx = -1e30f;
        for (int m = m0; m < m1; m++) mx = fmaxf(mx, row[m]);
        sred[prt * 64 + p] = mx;
        __syncthreads();
        mx = fmaxf(fmaxf(sred[p], sred[64 + p]), fmaxf(sred[128 + p], sred[192 + p]));
        float s = 0.f;
        for (int m = m0; m < m1; m++) {
            float e = expf(row[m] - mx);
            row[m] = e;
            s += e;
        }
        __syncthreads();
        sred[prt * 64 + p] = s;
        __syncthreads();
        s = sred[p] + sred[64 + p] + sred[128 + p] + sred[192 + p];
        float inv = 1.f / s;
        for (int m = m0; m < m1; m++) row[m] *= inv;
    }
    __syncthreads();
    // ---- build lgT[m][p] hi/lo bf16 (lane-consecutive p: conflict-free) ----
    for (int j = tid; j < 64 * 64; j += 256) {
        int m = j >> 6, p = j & 63;
        float w = (m < M_) ? lg[p * LSTR + m] : 0.f;
        unsigned short hi = f2b(w);
        lgTh[m * TSTR + p] = hi;
        lgTl[m * TSTR + p] = f2b(w - b2f(hi));
    }
    __syncthreads();
    // ---- topk on last iteration (reads+destroys lg; before xT overwrites) ---
    if (do_topk && tid < 64) {
        float* row = &lg[tid * LSTR];
        int* nb = nn + ((size_t)b * N_ + p0 + tid) * TK_;
        for (int r = 0; r < TK_; r++) {
            float bv = -1.f;
            int bi = 0;
            for (int m = 0; m < M_; m++) {
                float v = row[m];
                if (v > bv) { bv = v; bi = m; }   // strict > : lowest index wins ties
            }
            nb[r] = bi;
            row[bi] = -1.f;
        }
    }
    // ---- phase 2: part[m][c] = sum_p w*x via 3-term bf16-split MFMA ----
    f32x4 acc2[13];
#pragma unroll
    for (int i = 0; i < 13; i++) acc2[i] = (f32x4){0.f, 0.f, 0.f, 0.f};
    for (int h = 0; h < 2; h++) {
        __syncthreads();   // lg/topk done (h=0); prev MFMA reads done (h=1)
        // xT build: lanes consecutive pl -> contiguous b16 writes (no conflict)
        for (int j = tid; j < 32 * 24; j += 256) {
            int pl = j & 31, ko = (j >> 5) * 8;
            int4 vh = *(const int4*)&x16b[(size_t)(h * 32 + pl) * C_ + ko];
            int4 vl = *(const int4*)&x16lb[(size_t)(h * 32 + pl) * C_ + ko];
            const unsigned short* ph = (const unsigned short*)&vh;
            const unsigned short* pv = (const unsigned short*)&vl;
#pragma unroll
            for (int i = 0; i < 8; i++) {
                xTh[(ko + i) * XSTR + pl] = ph[i];
                xTl[(ko + i) * XSTR + pl] = pv[i];
            }
        }
        for (int j = tid; j < 32 * 16; j += 256) {
            int pl = j & 31, c = C_ + (j >> 5);
            xTh[c * XSTR + pl] = (c == C_) ? f2b(1.f) : 0;
            xTl[c * XSTR + pl] = 0;
        }
        __syncthreads();
        b16x8 ah = *(const b16x8*)&lgTh[(wave * 16 + m16) * TSTR + h * 32 + q * 8];
        b16x8 al = *(const b16x8*)&lgTl[(wave * 16 + m16) * TSTR + h * 32 + q * 8];
#pragma unroll
        for (int ct = 0; ct < 13; ct++) {
            b16x8 bh = *(const b16x8*)&xTh[(ct * 16 + m16) * XSTR + q * 8];
            b16x8 bl = *(const b16x8*)&xTl[(ct * 16 + m16) * XSTR + q * 8];
            acc2[ct] = __builtin_amdgcn_mfma_f32_16x16x32_bf16(ah, bh, acc2[ct], 0, 0, 0);
            acc2[ct] = __builtin_amdgcn_mfma_f32_16x16x32_bf16(ah, bl, acc2[ct], 0, 0, 0);
            acc2[ct] = __builtin_amdgcn_mfma_f32_16x16x32_bf16(al, bh, acc2[ct], 0, 0, 0);
        }
    }
    // ---- epilogue: D row m = wave*16 + q*4 + r, col c = ct*16 + m16 ----
    unsigned short* pb = part + ((size_t)b * CH_ + blk) * (size_t)(M_ * C_);
    int mbase = wave * 16 + q * 4;
#pragma unroll
    for (int ct = 0; ct < 13; ct++) {
        int c = ct * 16 + m16;
#pragma unroll
        for (int r = 0; r < 4; r++) {
            int mm = mbase + r;
            if (mm >= M_) continue;
            float v = acc2[ct][r];
            if (c < C_) pb[(size_t)mm * C_ + c] = f2b(v);
            else if (c == C_) wsp[((size_t)b * CH_ + blk) * M_ + mm] = v;
        }
    }
}

__global__ __launch_bounds__(192) void k_upd_reduce(const unsigned short* __restrict__ part,
        const float* __restrict__ wsp, float* __restrict__ cent, float* __restrict__ c2,
        unsigned short* __restrict__ cent16,
        unsigned short* __restrict__ centh, unsigned short* __restrict__ centl, int last) {
    int m = blockIdx.x, b = blockIdx.y, c = threadIdx.x;
    __shared__ float sws;
    __shared__ float red[3];
    if (c == 0) {
        float s = 0.f;
        for (int ch = 0; ch < CH_; ch++) s += wsp[((size_t)b * CH_ + ch) * M_ + m];
        sws = s + 1e-8f;
    }
    float s = 0.f;
    for (int ch = 0; ch < CH_; ch++)
        s += b2f(part[(((size_t)b * CH_ + ch) * M_ + m) * (size_t)C_ + c]);
    __syncthreads();
    float v = s / sws;
    size_t o = ((size_t)b * M_ + m) * C_ + c;
    cent[o] = v;
    if (last) cent16[o] = f2b(v);
    size_t oh = ((size_t)b * 64 + m) * C_ + c;
    unsigned short hi = f2b(v);
    centh[oh] = hi;
    centl[oh] = f2b(v - b2f(hi));
    float q = v * v;
#pragma unroll
    for (int off = 32; off > 0; off >>= 1) q += __shfl_down(q, off, 64);
    if ((c & 63) == 0) red[c >> 6] = q;
    __syncthreads();
    if (c == 0) c2[(size_t)b * M_ + m] = red[0] + red[1] + red[2];
}

// ---------------- gathers (bf16 sources): edge max-rel + topk-centroid max ---
__global__ __launch_bounds__(192) void k_gather(const unsigned short* __restrict__ xt16,
        const unsigned short* __restrict__ cent16, const int* __restrict__ edge,
        const int* __restrict__ nn, unsigned short* __restrict__ xjt16,
        unsigned short* __restrict__ xjct16) {
    __shared__ int sidx[2 * K_ + TK_];
    int p = blockIdx.x, b = blockIdx.y, c = threadIdx.x;
    if (c < K_)
        sidx[c] = edge[((size_t)b * N_ + p) * K_ + c];
    else if (c < 2 * K_)
        sidx[c] = edge[(size_t)B_ * N_ * K_ + ((size_t)b * N_ + p) * K_ + (c - K_)];
    else if (c < 2 * K_ + TK_)
        sidx[c] = nn[((size_t)b * N_ + p) * TK_ + (c - 2 * K_)];
    __syncthreads();
    const unsigned short* xb = xt16 + (size_t)b * N_ * C_;
    const unsigned short* cbv = cent16 + (size_t)b * M_ * C_;
    float xv = b2f(xb[(size_t)p * C_ + c]);
    float mj = -1e30f;
#pragma unroll
    for (int kk = 0; kk < K_; kk++) {
        float vj = b2f(xb[(size_t)sidx[kk] * C_ + c]);
        float vi = b2f(xb[(size_t)sidx[K_ + kk] * C_ + c]);
        mj = fmaxf(mj, vj - vi);
    }
    float mc = -1e30f;
#pragma unroll
    for (int kk = 0; kk < TK_; kk++)
        mc = fmaxf(mc, b2f(cbv[(size_t)sidx[2 * K_ + kk] * C_ + c]));
    size_t o = ((size_t)b * N_ + p) * C_ + c;
    xjt16[o] = f2b(mj);
    xjct16[o] = f2b(mc - xv);
}

// ------- final conv via bf16 MFMA: full-OC 192(o) x 64(p) tile, feat read once
__global__ __launch_bounds__(256) void k_gemm(const unsigned short* __restrict__ Wg16,
        const unsigned short* __restrict__ xt16, const unsigned short* __restrict__ xjt16,
        const unsigned short* __restrict__ xjct16, const float* __restrict__ bias,
        float* __restrict__ out) {
    __shared__ short As[192 * GSTR];   // Wg k-chunk [o][32k]
    __shared__ short Bs[64 * GSTR];    // feat k-chunk [p][32k]
    int b = blockIdx.y;
    int po = blockIdx.x * 64;
    int tid = threadIdx.x;
    int wave = tid >> 6, lane = tid & 63;
    int m16 = lane & 15, q = lane >> 4;
    const unsigned short* s0 = xt16 + (size_t)b * N_ * C_;
    const unsigned short* s1 = xjt16 + (size_t)b * N_ * C_;
    const unsigned short* s2 = xjct16 + (size_t)b * N_ * C_;
    f32x4 acc[12];
#pragma unroll
    for (int i = 0; i < 12; i++) acc[i] = (f32x4){0.f, 0.f, 0.f, 0.f};
    int brow = tid >> 2, bch = tid & 3;
    for (int kt = 0; kt < 18; kt++) {
        int kg = kt * 32;
        int prt = kg / C_, koff = kg - prt * C_;
        const unsigned short* src = (prt == 0) ? s0 : ((prt == 1) ? s1 : s2);
        int4 av[3];
#pragma unroll
        for (int t = 0; t < 3; t++) {
            int idx = t * 256 + tid;
            av[t] = *(const int4*)&Wg16[(size_t)(idx >> 2) * KC_ + kg + (idx & 3) * 8];
        }
        int4 bv = *(const int4*)&src[(size_t)(po + brow) * C_ + koff + bch * 8];
        __syncthreads();
#pragma unroll
        for (int t = 0; t < 3; t++) {
            int idx = t * 256 + tid;
            *(int4*)&As[(idx >> 2) * GSTR + (idx & 3) * 8] = av[t];
        }
        *(int4*)&Bs[brow * GSTR + bch * 8] = bv;
        __syncthreads();
        b16x8 bf = *(const b16x8*)&Bs[(wave * 16 + m16) * GSTR + q * 8];
#pragma unroll
        for (int of = 0; of < 12; of++) {
            b16x8 af = *(const b16x8*)&As[(of * 16 + m16) * GSTR + q * 8];
            acc[of] = __builtin_amdgcn_mfma_f32_16x16x32_bf16(af, bf, acc[of], 0, 0, 0);
        }
    }
    int p = po + wave * 16 + m16;
#pragma unroll
    for (int of = 0; of < 12; of++) {
        int o = of * 16 + q * 4;
        float4 bv = *(const float4*)&bias[o];
        float bia[4] = {bv.x, bv.y, bv.z, bv.w};
#pragma unroll
        for (int r = 0; r < 4; r++)
            out[((size_t)b * OC_ + o + r) * N_ + p] = fmaxf(acc[of][r] + bia[r], 0.f);
    }
}

extern "C" void kernel_launch(void* const* d_in, const int* in_sizes, int n_in,
                              void* d_out, int out_size, void* d_ws, size_t ws_size,
                              hipStream_t stream) {
    (void)in_sizes; (void)n_in; (void)out_size; (void)ws_size;
    const float* x   = (const float*)d_in[0];
    const int* edge  = (const int*)d_in[1];
    const float* cw  = (const float*)d_in[2];
    const float* cbi = (const float*)d_in[3];
    float* ws = (float*)d_ws;
    size_t o = 0;
    float* xt   = ws + o; o += (size_t)B_ * N_ * C_;
    unsigned short* xt16 = (unsigned short*)(ws + o); o += (size_t)B_ * N_ * C_ / 2;
    unsigned short* xt16l = (unsigned short*)(ws + o); o += (size_t)B_ * N_ * C_ / 2;
    unsigned short* Wg16 = (unsigned short*)(ws + o); o += (size_t)OC_ * KC_ / 2;
    float* cent = ws + o; o += (size_t)B_ * M_ * C_;
    unsigned short* cent16 = (unsigned short*)(ws + o); o += (size_t)B_ * M_ * C_ / 2;
    unsigned short* centh = (unsigned short*)(ws + o); o += (size_t)B_ * 64 * C_ / 2;
    unsigned short* centl = (unsigned short*)(ws + o); o += (size_t)B_ * 64 * C_ / 2;
    float* c2   = ws + o; o += (size_t)B_ * M_;
    unsigned short* part = (unsigned short*)(ws + o); o += (size_t)B_ * CH_ * M_ * C_ / 2;
    float* wsp  = ws + o; o += (size_t)B_ * CH_ * M_;
    int* nn = (int*)(ws + o); o += (size_t)B_ * N_ * TK_;
    unsigned short* xjt16  = (unsigned short*)(ws + o); o += (size_t)B_ * N_ * C_ / 2;
    unsigned short* xjct16 = (unsigned short*)(ws + o); o += (size_t)B_ * N_ * C_ / 2;
    float* outp = (float*)d_out;

    k_transpose<<<dim3(218, C_ / 32, B_), dim3(32, 8), 0, stream>>>(x, xt, xt16, xt16l, cw, Wg16);
    k_init_cent<<<dim3(64, B_), dim3(192), 0, stream>>>(xt, cent, c2, centh, centl);
    for (int it = 0; it < 3; it++) {
        k_logits_upd<<<dim3(CH_, B_), dim3(256), 0, stream>>>(xt, xt16, xt16l, cent,
            centh, centl, c2, part, wsp, nn, (it == 2) ? 1 : 0, (it < 2) ? 1 : 0);
        k_upd_reduce<<<dim3(M_, B_), dim3(192), 0, stream>>>(part, wsp, cent, c2,
            cent16, centh, centl, (it == 2) ? 1 : 0);
    }
    k_gather<<<dim3(N_, B_), dim3(192), 0, stream>>>(xt16, cent16, edge, nn, xjt16, xjct16);
    k_gemm<<<dim3(N_ / 64, B_), dim3(256), 0, stream>>>(Wg16, xt16, xjt16, xjct16, cbi, outp);
}